// Round 14
// baseline (364.460 us; speedup 1.0000x reference)
//
#include <hip/hip_runtime.h>
#include <math.h>
#include <stdint.h>
#include <stddef.h>

typedef _Float16 f16;
typedef _Float16 f16x8 __attribute__((ext_vector_type(8)));
typedef _Float16 f16x4 __attribute__((ext_vector_type(4)));
typedef __fp16 fp16x2 __attribute__((ext_vector_type(2)));
typedef float f32x4 __attribute__((ext_vector_type(4)));
typedef float f32x16 __attribute__((ext_vector_type(16)));
typedef float fvec4 __attribute__((ext_vector_type(4)));
typedef unsigned int u32x4 __attribute__((ext_vector_type(4)));
typedef int i32x2 __attribute__((ext_vector_type(2)));

#define MFMA16F16(a, b, c) __builtin_amdgcn_mfma_f32_16x16x32_f16((a), (b), (c), 0, 0, 0)
#define MFMA32F16(a, b, c) __builtin_amdgcn_mfma_f32_32x32x16_f16((a), (b), (c), 0, 0, 0)

static constexpr int kT = 2048;
static constexpr int kB = 4;
static constexpr int kD = 1024;
static constexpr int kNH = 16;
static constexpr int kM = kB * kT;  // 8192
static constexpr int kMAXL = 100;
static constexpr float kLOG2E = 1.4426950408889634f;

// ---------------- workspace layout (bytes) ----------------
static constexpr size_t SZ_XH = (size_t)kM * kD * 2;  // 16 MB fp16
static constexpr size_t SZ_W = (size_t)kD * kD * 2;   // 2 MB fp16
static constexpr size_t OFF_TAB = 0;                  // 16*101 floats + (1-w)
static constexpr size_t OFF_XH = 8192;
static constexpr size_t OFF_WQ = OFF_XH + SZ_XH;
static constexpr size_t OFF_WK = OFF_WQ + SZ_W;
static constexpr size_t OFF_WV = OFF_WK + SZ_W;
static constexpr size_t OFF_WF = OFF_WV + SZ_W;
static constexpr size_t OFF_Q = OFF_WF + SZ_W;
static constexpr size_t OFF_K = OFF_Q + SZ_XH;
static constexpr size_t OFF_V = OFF_K + SZ_XH;   // holds V^T [1024][8192]
static constexpr size_t OFF_P = OFF_V + SZ_XH;   // blended (blend@V) fp16
static constexpr size_t WS_NEED = OFF_P + SZ_XH; // ~92 MB

__device__ __forceinline__ unsigned int pk_f16(float a, float b) {
  fp16x2 h = __builtin_amdgcn_cvt_pkrtz(a, b);
  return __builtin_bit_cast(unsigned int, h);
}

// v_permlane32_swap_b32: ret.x = [a(0:31) | b(0:31)], ret.y = [a(32:63) | b(32:63)]
__device__ __forceinline__ i32x2 pl32swap(unsigned a, unsigned b) {
  return __builtin_amdgcn_permlane32_swap((int)a, (int)b, false, false);
}

// ---------------- fused preprocessing: tab + all 5 fp32->fp16 converts --------------
// One dispatch replaces 6 (R13 win, -13.5 us): blocks 0..2047 convert x (grid-stride);
// blocks 2048..3071 convert the 4 weight matrices; block 0 also computes the P table.
__global__ void pre_kernel(const float* __restrict__ x, const float* __restrict__ Wq,
                           const float* __restrict__ Wk, const float* __restrict__ Wv,
                           const float* __restrict__ Wf, const float* __restrict__ mu,
                           const float* __restrict__ lam, const float* __restrict__ g1,
                           const float* __restrict__ g2, const float* __restrict__ th1,
                           const float* __restrict__ th2, f16* __restrict__ xh,
                           f16* __restrict__ wqh, f16* __restrict__ wkh, f16* __restrict__ wvh,
                           f16* __restrict__ wfh, float* __restrict__ tab) {
  const int b = blockIdx.x;
  if (b == 0) {  // P table (in addition to this block's cvt share)
    const float w = 1.0f / (1.0f + expf(-mu[0]));
    for (int e = threadIdx.x; e < kNH * (kMAXL + 1); e += blockDim.x) {
      const int h = e / (kMAXL + 1);
      const int L = e - h * (kMAXL + 1);
      const float Lf = (float)L;
      float v;
      if (h < 4) {
        const float base = lam[h];
        const float mag = expf(Lf * logf(fabsf(base)));
        const float sgn = (base < 0.0f && (L & 1)) ? -1.0f : 1.0f;
        v = mag * sgn;
      } else if (h < 10) {
        const int s = h - 4;
        v = expf(Lf * logf(g1[s])) * sinf(th1[s] * Lf);
      } else {
        const int s = h - 10;
        v = expf(Lf * logf(g2[s])) * cosf(th2[s] * Lf);
      }
      tab[e] = w * v;
    }
    if (threadIdx.x == 0) tab[kNH * (kMAXL + 1)] = 1.0f - w;
  }

  const float* src;
  f16* dst;
  int n4, i0, nb;
  if (b < 2048) {  // x: 2M f16x4 groups over 2048 blocks
    src = x; dst = xh; n4 = kM * kD / 4; i0 = b; nb = 2048;
  } else {
    const int wsel = (b - 2048) >> 8;  // 0..3
    const int wb = (b - 2048) & 255;
    src = (wsel == 0) ? Wq : ((wsel == 1) ? Wk : ((wsel == 2) ? Wv : Wf));
    dst = (wsel == 0) ? wqh : ((wsel == 1) ? wkh : ((wsel == 2) ? wvh : wfh));
    n4 = kD * kD / 4; i0 = wb; nb = 256;
  }
  for (int i = i0 * 256 + threadIdx.x; i < n4; i += nb * 256) {
    fvec4 v = ((const fvec4*)src)[i];
    f16x4 o;
    o[0] = (f16)v[0]; o[1] = (f16)v[1]; o[2] = (f16)v[2]; o[3] = (f16)v[3];
    ((f16x4*)dst)[i] = o;
  }
}

// ---------------- C[m,n] = sum_k A[m,k]*B[n,k] (+bias) * oscale ----------------
// 128x128 tile, BK=32, 4 waves each 64x64, 16x16x32 f16 MFMA, register-prefetch staging.
template <typename OutT, bool BIAS_ROW>
__global__ __launch_bounds__(256, 3) void gemm_bt_kernel(
    const f16* __restrict__ A, const f16* __restrict__ B, const float* __restrict__ bias,
    OutT* __restrict__ C, int M, int N, int K, float oscale) {
  __shared__ f16 As[128][32];
  __shared__ f16 Bs[128][32];
  const int tid = threadIdx.x;
  const int lane = tid & 63;
  const int wave = tid >> 6;
  const int quad = lane >> 4;
  const int l16 = lane & 15;
  const int nb = N >> 7;
  const int bm = blockIdx.x / nb;
  const int bn = blockIdx.x - bm * nb;
  const int m0 = bm << 7;
  const int n0 = bn << 7;
  const int wm = (wave & 1) << 6;
  const int wn = (wave >> 1) << 6;

  const int srow = tid >> 2;        // 0..63
  const int scol = (tid & 3) << 3;  // 0,8,16,24
  const f16* Ap = A + (size_t)(m0 + srow) * K + scol;
  const f16* Bp = B + (size_t)(n0 + srow) * K + scol;
  const size_t rstep = (size_t)64 * K;

  f32x4 acc[4][4];
#pragma unroll
  for (int i = 0; i < 4; i++)
#pragma unroll
    for (int j = 0; j < 4; j++) acc[i][j] = (f32x4){0.f, 0.f, 0.f, 0.f};

  f16x8 ra0 = *(const f16x8*)(Ap);
  f16x8 ra1 = *(const f16x8*)(Ap + rstep);
  f16x8 rb0 = *(const f16x8*)(Bp);
  f16x8 rb1 = *(const f16x8*)(Bp + rstep);

  for (int k0 = 0; k0 < K; k0 += 32) {
    __syncthreads();
    *(f16x8*)&As[srow][scol] = ra0;
    *(f16x8*)&As[srow + 64][scol] = ra1;
    *(f16x8*)&Bs[srow][scol] = rb0;
    *(f16x8*)&Bs[srow + 64][scol] = rb1;
    __syncthreads();
    if (k0 + 32 < K) {  // prefetch next K-slab while computing
      ra0 = *(const f16x8*)(Ap + (k0 + 32));
      ra1 = *(const f16x8*)(Ap + rstep + (k0 + 32));
      rb0 = *(const f16x8*)(Bp + (k0 + 32));
      rb1 = *(const f16x8*)(Bp + rstep + (k0 + 32));
    }
    f16x8 af[4], bf[4];
#pragma unroll
    for (int i = 0; i < 4; i++) af[i] = *(const f16x8*)&As[wm + i * 16 + l16][quad * 8];
#pragma unroll
    for (int i = 0; i < 4; i++) bf[i] = *(const f16x8*)&Bs[wn + i * 16 + l16][quad * 8];
#pragma unroll
    for (int mi = 0; mi < 4; mi++)
#pragma unroll
      for (int ni = 0; ni < 4; ni++) acc[mi][ni] = MFMA16F16(af[mi], bf[ni], acc[mi][ni]);
  }

#pragma unroll
  for (int mi = 0; mi < 4; mi++) {
    const int rbase = m0 + wm + mi * 16 + quad * 4;
#pragma unroll
    for (int ni = 0; ni < 4; ni++) {
      const int gc = n0 + wn + ni * 16 + l16;
      const float bcol = BIAS_ROW ? 0.0f : bias[gc];
#pragma unroll
      for (int r = 0; r < 4; r++) {
        const int gr = rbase + r;
        float v = acc[mi][ni][r] + (BIAS_ROW ? bias[gr] : bcol);
        v *= oscale;
        C[(size_t)gr * N + gc] = (OutT)v;
      }
    }
  }
}

// ---------------- fused Q/K/V^T projection (one 1536-block dispatch) ----------------
__global__ __launch_bounds__(256, 3) void qkv_kernel(
    const f16* __restrict__ xh, const f16* __restrict__ wq, const f16* __restrict__ wk,
    const f16* __restrict__ wv, const float* __restrict__ bq, const float* __restrict__ bk,
    const float* __restrict__ bv, f16* __restrict__ Qp, f16* __restrict__ Kp,
    f16* __restrict__ Vt) {
  __shared__ f16 As[128][32];
  __shared__ f16 Bs[128][32];
  const int g = blockIdx.x >> 9;      // 0,1,2
  const int inner = blockIdx.x & 511; // 0..511
  const f16* A = (g == 2) ? wv : xh;
  const f16* B = (g == 0) ? wq : ((g == 1) ? wk : xh);
  const float* bias = (g == 0) ? bq : ((g == 1) ? bk : bv);
  f16* C = (g == 0) ? Qp : ((g == 1) ? Kp : Vt);
  const int N = (g == 2) ? kM : kD;
  const int K = kD;
  const float oscale = (g == 0) ? kLOG2E : 1.0f;
  const bool bias_row = (g == 2);
  const int nbs = (g == 2) ? 6 : 3;  // log2(N/128)

  const int tid = threadIdx.x;
  const int lane = tid & 63;
  const int wave = tid >> 6;
  const int quad = lane >> 4;
  const int l16 = lane & 15;
  const int bm = inner >> nbs;
  const int bn = inner & ((1 << nbs) - 1);
  const int m0 = bm << 7;
  const int n0 = bn << 7;
  const int wm = (wave & 1) << 6;
  const int wn = (wave >> 1) << 6;

  const int srow = tid >> 2;
  const int scol = (tid & 3) << 3;
  const f16* Ap = A + (size_t)(m0 + srow) * K + scol;
  const f16* Bp = B + (size_t)(n0 + srow) * K + scol;
  const size_t rstep = (size_t)64 * K;

  f32x4 acc[4][4];
#pragma unroll
  for (int i = 0; i < 4; i++)
#pragma unroll
    for (int j = 0; j < 4; j++) acc[i][j] = (f32x4){0.f, 0.f, 0.f, 0.f};

  f16x8 ra0 = *(const f16x8*)(Ap);
  f16x8 ra1 = *(const f16x8*)(Ap + rstep);
  f16x8 rb0 = *(const f16x8*)(Bp);
  f16x8 rb1 = *(const f16x8*)(Bp + rstep);

  for (int k0 = 0; k0 < K; k0 += 32) {
    __syncthreads();
    *(f16x8*)&As[srow][scol] = ra0;
    *(f16x8*)&As[srow + 64][scol] = ra1;
    *(f16x8*)&Bs[srow][scol] = rb0;
    *(f16x8*)&Bs[srow + 64][scol] = rb1;
    __syncthreads();
    if (k0 + 32 < K) {
      ra0 = *(const f16x8*)(Ap + (k0 + 32));
      ra1 = *(const f16x8*)(Ap + rstep + (k0 + 32));
      rb0 = *(const f16x8*)(Bp + (k0 + 32));
      rb1 = *(const f16x8*)(Bp + rstep + (k0 + 32));
    }
    f16x8 af[4], bf[4];
#pragma unroll
    for (int i = 0; i < 4; i++) af[i] = *(const f16x8*)&As[wm + i * 16 + l16][quad * 8];
#pragma unroll
    for (int i = 0; i < 4; i++) bf[i] = *(const f16x8*)&Bs[wn + i * 16 + l16][quad * 8];
#pragma unroll
    for (int mi = 0; mi < 4; mi++)
#pragma unroll
      for (int ni = 0; ni < 4; ni++) acc[mi][ni] = MFMA16F16(af[mi], bf[ni], acc[mi][ni]);
  }

#pragma unroll
  for (int mi = 0; mi < 4; mi++) {
    const int rbase = m0 + wm + mi * 16 + quad * 4;
#pragma unroll
    for (int ni = 0; ni < 4; ni++) {
      const int gc = n0 + wn + ni * 16 + l16;
      const float bcol = bias_row ? 0.0f : bias[gc];
#pragma unroll
      for (int r = 0; r < 4; r++) {
        const int gr = rbase + r;
        float v = acc[mi][ni][r] + (bias_row ? bias[gr] : bcol);
        v *= oscale;
        C[(size_t)gr * N + gc] = (f16)v;
      }
    }
  }
}

// ---------------- fused attention + positional blend, 32x32 MFMA / O^T form ----------
// R9 structure (attn 144.4 us) + R14 band-fold. S^T = K@Q^T via mfma_f32_32x32x16 (lane
// owns one q-column); defer-max softmax (THR=8); O^T = V^T @ P^T via permlane32_swap
// fragments; denominator via ones@P^T MFMA; LDS un-transpose epilogue.
// R14: near-diagonal band folded into the main loop at j0 in {qblk-128, qblk} (R10
// verified correct; R10's regression was the s[4] merged-softmax spill, NOT the fold —
// here s[2] is dead when the band block runs). Deletes the band epilogue: -2 barrier
// pairs, -2 V restages.
// MEASURED constraints (do not re-try):
//  - R5: 4 blocks/CU -> L2 thrash, HBM 4.4x. L2 residency > wave residency.
//  - R7: T14 reg-prefetch of next K/V tile -> 2-tile footprint -> L2 spill, HBM 2.5x.
//  - R8: s_setprio: +6 us (4-wave lockstep blocks starve VALU waves).
//  - R10: merged-128j softmax (s[4] live) -> reg-budget overflow -> scratch spills.
__global__ __launch_bounds__(256, 3) void attn_kernel(
    const f16* __restrict__ Qh, const f16* __restrict__ Kh, const f16* __restrict__ Vt,
    const float* __restrict__ tabg, f16* __restrict__ Pb) {
  __shared__ f16 Ks[128][68];   // K tile [j][d], +4 pad: row stride 34 dw -> 2-way banks
  __shared__ f16 Vs[64][132];   // V^T tile [d][j], +4 pad: row stride 66 dw -> 2-way
  __shared__ float tab_s[101];

  const int tid = threadIdx.x;
  const int lane = tid & 63;
  const int wave = tid >> 6;
  const int l31 = lane & 31;
  const int hi = lane >> 5;
  const int hi8 = hi * 8;
  // XCD-affinity decode
  const int xcd = blockIdx.x & 7;
  const int rest = blockIdx.x >> 3;         // 0..127
  const int qt = rest & 15;
  const int combo = (rest >> 4) * 8 + xcd;  // 0..63 == bi*16 + h
  const int h = combo & 15;
  const int bi = combo >> 4;

  if (tid < 101) tab_s[tid] = tabg[h * 101 + tid];
  const float one_m_w = tabg[kNH * 101];
  const float tab100f = tabg[h * 101 + kMAXL];

  const int qblk = qt * 128;
  const int qw0 = qblk + wave * 32;  // wave's q base (32 q per wave)
  const int qg = qw0 + l31;          // this lane's q (t-local)
  const size_t bt0 = (size_t)bi * kT;

  // Q^T B-fragments: B[k=d][col=q], lane col=q=l31, k = hi*8+e, d = kc*16+hi*8+e
  f16x8 qf[4];
#pragma unroll
  for (int kc = 0; kc < 4; kc++)
    qf[kc] = *(const f16x8*)(Qh + (bt0 + qg) * kD + h * 64 + kc * 16 + hi8);

  f32x16 Oat[2], Opc[2];  // O^T accumulators: row=d (dt*32 + pattern), col=q
  f32x16 Lacc;            // softmax denominator accumulator (only [0] meaningful)
#pragma unroll
  for (int dt = 0; dt < 2; dt++)
#pragma unroll
    for (int r = 0; r < 16; r++) {
      Oat[dt][r] = 0.f;
      Opc[dt][r] = 0.f;
    }
#pragma unroll
  for (int r = 0; r < 16; r++) Lacc[r] = 0.f;
  float mrow = -INFINITY;

  const int sr8 = tid >> 3, sp8 = tid & 7;
  const int sr16 = tid >> 4, sp16 = tid & 15;

  f16x8 cf, ones;  // splat tab[100] fragment; all-ones A fragment for denominator
  {
    const f16 cth = (f16)tab100f;
#pragma unroll
    for (int ii = 0; ii < 8; ii++) {
      cf[ii] = cth;
      ones[ii] = (f16)1.0f;
    }
  }

  for (int j0 = 0; j0 < kT; j0 += 128) {
    __syncthreads();
    // stage K tile [j][d]
#pragma unroll
    for (int u = 0; u < 4; u++) {
      const int jr = sr8 + u * 32;
      *(f16x8*)&Ks[jr][sp8 * 8] = *(const f16x8*)(Kh + (bt0 + j0 + jr) * kD + h * 64 + sp8 * 8);
    }
    // stage V^T tile [d][j]
#pragma unroll
    for (int u = 0; u < 4; u++) {
      const int d = sr16 + u * 16;
      *(f16x8*)&Vs[d][sp16 * 8] =
          *(const f16x8*)(Vt + (size_t)(h * 64 + d) * kM + bt0 + j0 + sp16 * 8);
    }
    __syncthreads();

#pragma unroll
    for (int c = 0; c < 2; c++) {  // 64-j chunks
      // S^T = K Q^T : two 32-j tiles, contraction over d in 4 chunks of 16
      f32x16 s[2];
#pragma unroll
      for (int jt = 0; jt < 2; jt++)
#pragma unroll
        for (int r = 0; r < 16; r++) s[jt][r] = 0.f;
#pragma unroll
      for (int kc = 0; kc < 4; kc++) {
        f16x8 ka = *(const f16x8*)&Ks[c * 64 + l31][kc * 16 + hi8];
        f16x8 kb = *(const f16x8*)&Ks[c * 64 + 32 + l31][kc * 16 + hi8];
        s[0] = MFMA32F16(ka, qf[kc], s[0]);
        s[1] = MFMA32F16(kb, qf[kc], s[1]);
      }

      // online softmax with defer-max: lane owns column q; rows split lane<->lane^32
      float mx = s[0][0];
#pragma unroll
      for (int jt = 0; jt < 2; jt++)
#pragma unroll
        for (int r = 0; r < 16; r++) mx = fmaxf(mx, s[jt][r]);
      mx = fmaxf(mx, __shfl_xor(mx, 32));
      if (!__all(mx <= mrow + 8.0f)) {  // raise running max only when needed
        const float mnew = fmaxf(mrow, mx);
        const float al = __builtin_amdgcn_exp2f(mrow - mnew);
        mrow = mnew;
#pragma unroll
        for (int dt = 0; dt < 2; dt++)
#pragma unroll
          for (int r = 0; r < 16; r++) Oat[dt][r] *= al;
        Lacc[0] *= al;
      }

#pragma unroll
      for (int jt = 0; jt < 2; jt++) {
        // exp2 + pack: w[k] covers j-row pairs (2k,2k+1) of this jt tile's lane half
        unsigned w[8];
#pragma unroll
        for (int k = 0; k < 8; k++) {
          const float e0 = __builtin_amdgcn_exp2f(s[jt][2 * k] - mrow);
          const float e1 = __builtin_amdgcn_exp2f(s[jt][2 * k + 1] - mrow);
          w[k] = pk_f16(e0, e1);
        }
        // P^T B-fragments via permlane32_swap:
        //  even 16-j half: words = {sw(w0,w2).x, sw(w1,w3).x, sw(w0,w2).y, sw(w1,w3).y}
        //  odd  16-j half: same with w4..w7
        i32x2 a0 = pl32swap(w[0], w[2]);
        i32x2 a1 = pl32swap(w[1], w[3]);
        i32x2 b0 = pl32swap(w[4], w[6]);
        i32x2 b1 = pl32swap(w[5], w[7]);
        u32x4 ue = {(unsigned)a0.x, (unsigned)a1.x, (unsigned)a0.y, (unsigned)a1.y};
        u32x4 uo = {(unsigned)b0.x, (unsigned)b1.x, (unsigned)b0.y, (unsigned)b1.y};
        const f16x8 fe = __builtin_bit_cast(f16x8, ue);
        const f16x8 fo = __builtin_bit_cast(f16x8, uo);
        // O^T += V^T @ P^T over this jt tile's two 16-j chunks; denominator via ones@P^T
#pragma unroll
        for (int dt = 0; dt < 2; dt++) {
          f16x8 ve = *(const f16x8*)&Vs[dt * 32 + l31][c * 64 + jt * 32 + hi8];
          Oat[dt] = MFMA32F16(ve, fe, Oat[dt]);
        }
        Lacc = MFMA32F16(ones, fe, Lacc);
#pragma unroll
        for (int dt = 0; dt < 2; dt++) {
          f16x8 vo = *(const f16x8*)&Vs[dt * 32 + l31][c * 64 + jt * 32 + 16 + hi8];
          Oat[dt] = MFMA32F16(vo, fo, Oat[dt]);
        }
        Lacc = MFMA32F16(ones, fo, Lacc);
      }
    }

    // constant positional region: whole tile is tab[100]
    if (j0 + 228 <= qw0) {
#pragma unroll
      for (int jc = 0; jc < 8; jc++)
#pragma unroll
        for (int dt = 0; dt < 2; dt++) {
          f16x8 vf = *(const f16x8*)&Vs[dt * 32 + l31][jc * 16 + hi8];
          Opc[dt] = MFMA32F16(vf, cf, Opc[dt]);
        }
    }

    // near-diagonal band folded in (block-uniform condition): w*P for the two boundary
    // tiles, accumulated into Opc (unscaled) while Vs is already staged. s[2] is dead
    // here, so peak register pressure is unchanged (R10 lesson).
    if (j0 == qblk - 128 || j0 == qblk) {
#pragma unroll
      for (int jc = 0; jc < 8; jc++) {
        f16x8 wf;
#pragma unroll
        for (int e = 0; e < 8; e++) {
          const int j = j0 + jc * 16 + hi8 + e;
          const int dlt = qg - j;
          float pv = 0.0f;
          if (dlt > 0) pv = tab_s[dlt > kMAXL ? kMAXL : dlt];
          wf[e] = (f16)pv;
        }
#pragma unroll
        for (int dt = 0; dt < 2; dt++) {
          f16x8 vf = *(const f16x8*)&Vs[dt * 32 + l31][jc * 16 + hi8];
          Opc[dt] = MFMA32F16(vf, wf, Opc[dt]);
        }
      }
    }
  }

  // scale attention by (1-w)/l (lane-uniform!) and fold in const-P + band
  {
    const float inv = one_m_w / Lacc[0];
#pragma unroll
    for (int dt = 0; dt < 2; dt++)
#pragma unroll
      for (int r = 0; r < 16; r++) Oat[dt][r] = Oat[dt][r] * inv + Opc[dt][r];
  }

  // epilogue: un-transpose O^T -> Pb[q][d] via per-wave LDS scratch (reuses Ks).
  // Barrier needed: other waves may still be reading Ks rows in their last QK.
  __syncthreads();
  {
    f16* sw = &Ks[wave * 32][0];  // viewed as [32 q][68]
#pragma unroll
    for (int dt = 0; dt < 2; dt++)
#pragma unroll
      for (int r = 0; r < 16; r++) {
        const int d = dt * 32 + (r & 3) + 8 * (r >> 2) + 4 * hi;
        sw[l31 * 68 + d] = (f16)Oat[dt][r];
      }
    // in-wave LDS write->read ordering handled by compiler (lgkmcnt)
#pragma unroll
    for (int u = 0; u < 4; u++) {
      const int qr = lane >> 1;
      const int c0 = (lane & 1) * 32 + u * 8;
      f16x8 ofr = *(const f16x8*)&sw[qr * 68 + c0];
      *(f16x8*)(Pb + (bt0 + qw0 + qr) * kD + h * 64 + c0) = ofr;
    }
  }
}

extern "C" void kernel_launch(void* const* d_in, const int* in_sizes, int n_in, void* d_out,
                              int out_size, void* d_ws, size_t ws_size, hipStream_t stream) {
  const float* x = (const float*)d_in[0];
  const float* mu = (const float*)d_in[1];
  const float* lam = (const float*)d_in[2];
  const float* g1 = (const float*)d_in[3];
  const float* g2 = (const float*)d_in[4];
  const float* th1 = (const float*)d_in[5];
  const float* th2 = (const float*)d_in[6];
  const float* Wq = (const float*)d_in[7];
  const float* bq = (const float*)d_in[8];
  const float* Wk = (const float*)d_in[9];
  const float* bk = (const float*)d_in[10];
  const float* Wv = (const float*)d_in[11];
  const float* bv = (const float*)d_in[12];
  const float* Wf = (const float*)d_in[13];
  const float* bf = (const float*)d_in[14];

  if (ws_size < WS_NEED) return;  // cannot run without scratch

  char* ws = (char*)d_ws;
  float* tab = (float*)(ws + OFF_TAB);
  f16* xh = (f16*)(ws + OFF_XH);
  f16* wqh = (f16*)(ws + OFF_WQ);
  f16* wkh = (f16*)(ws + OFF_WK);
  f16* wvh = (f16*)(ws + OFF_WV);
  f16* wfh = (f16*)(ws + OFF_WF);
  f16* Qp = (f16*)(ws + OFF_Q);
  f16* Kp = (f16*)(ws + OFF_K);
  f16* Vtp = (f16*)(ws + OFF_V);
  f16* Pbp = (f16*)(ws + OFF_P);

  // fused preprocessing: tab + all fp32->fp16 converts in ONE dispatch
  pre_kernel<<<3072, 256, 0, stream>>>(x, Wq, Wk, Wv, Wf, mu, lam, g1, g2, th1, th2, xh, wqh,
                                       wkh, wvh, wfh, tab);

  // fused Q/K/V^T projections (Q scaled by log2(e) after bias for exp2 softmax).
  qkv_kernel<<<1536, 256, 0, stream>>>(xh, wqh, wkh, wvh, bq, bk, bv, Qp, Kp, Vtp);

  attn_kernel<<<1024, 256, 0, stream>>>(Qp, Kp, Vtp, tab, Pbp);

  gemm_bt_kernel<float, false><<<512, 256, 0, stream>>>(Pbp, wfh, bf, (float*)d_out, kM, kD, kD,
                                                        1.0f);
}

// Round 15
// 346.277 us; speedup vs baseline: 1.0525x; 1.0525x over previous
//
#include <hip/hip_runtime.h>
#include <math.h>
#include <stdint.h>
#include <stddef.h>

typedef _Float16 f16;
typedef _Float16 f16x8 __attribute__((ext_vector_type(8)));
typedef _Float16 f16x4 __attribute__((ext_vector_type(4)));
typedef __fp16 fp16x2 __attribute__((ext_vector_type(2)));
typedef float f32x4 __attribute__((ext_vector_type(4)));
typedef float f32x16 __attribute__((ext_vector_type(16)));
typedef float fvec4 __attribute__((ext_vector_type(4)));
typedef unsigned int u32x4 __attribute__((ext_vector_type(4)));
typedef int i32x2 __attribute__((ext_vector_type(2)));

#define MFMA16F16(a, b, c) __builtin_amdgcn_mfma_f32_16x16x32_f16((a), (b), (c), 0, 0, 0)
#define MFMA32F16(a, b, c) __builtin_amdgcn_mfma_f32_32x32x16_f16((a), (b), (c), 0, 0, 0)

static constexpr int kT = 2048;
static constexpr int kB = 4;
static constexpr int kD = 1024;
static constexpr int kNH = 16;
static constexpr int kM = kB * kT;  // 8192
static constexpr int kMAXL = 100;
static constexpr float kLOG2E = 1.4426950408889634f;

// ---------------- workspace layout (bytes) ----------------
static constexpr size_t SZ_XH = (size_t)kM * kD * 2;  // 16 MB fp16
static constexpr size_t SZ_W = (size_t)kD * kD * 2;   // 2 MB fp16
static constexpr size_t OFF_TAB = 0;                  // 16*101 floats + (1-w)
static constexpr size_t OFF_XH = 8192;
static constexpr size_t OFF_WQ = OFF_XH + SZ_XH;
static constexpr size_t OFF_WK = OFF_WQ + SZ_W;
static constexpr size_t OFF_WV = OFF_WK + SZ_W;
static constexpr size_t OFF_WF = OFF_WV + SZ_W;
static constexpr size_t OFF_Q = OFF_WF + SZ_W;
static constexpr size_t OFF_K = OFF_Q + SZ_XH;
static constexpr size_t OFF_V = OFF_K + SZ_XH;   // holds V^T [1024][8192]
static constexpr size_t OFF_P = OFF_V + SZ_XH;   // blended (blend@V) fp16
static constexpr size_t WS_NEED = OFF_P + SZ_XH; // ~92 MB
// V^T prefix-column-sum table (64 KB of floats) ALIASES xh: xh is dead after qkv, and
// vsum runs after qkv. Vpre[(bi*16+h)*16 + p][d] = sum_{j < p*128} V^T[d][j] (f32).
static constexpr size_t OFF_VPRE = OFF_XH;

__device__ __forceinline__ unsigned int pk_f16(float a, float b) {
  fp16x2 h = __builtin_amdgcn_cvt_pkrtz(a, b);
  return __builtin_bit_cast(unsigned int, h);
}

// v_permlane32_swap_b32: ret.x = [a(0:31) | b(0:31)], ret.y = [a(32:63) | b(32:63)]
__device__ __forceinline__ i32x2 pl32swap(unsigned a, unsigned b) {
  return __builtin_amdgcn_permlane32_swap((int)a, (int)b, false, false);
}

// ---------------- fused preprocessing: tab + all 5 fp32->fp16 converts --------------
// One dispatch replaces 6 (R13 win, -13.5 us): blocks 0..2047 convert x (grid-stride);
// blocks 2048..3071 convert the 4 weight matrices; block 0 also computes the P table.
__global__ void pre_kernel(const float* __restrict__ x, const float* __restrict__ Wq,
                           const float* __restrict__ Wk, const float* __restrict__ Wv,
                           const float* __restrict__ Wf, const float* __restrict__ mu,
                           const float* __restrict__ lam, const float* __restrict__ g1,
                           const float* __restrict__ g2, const float* __restrict__ th1,
                           const float* __restrict__ th2, f16* __restrict__ xh,
                           f16* __restrict__ wqh, f16* __restrict__ wkh, f16* __restrict__ wvh,
                           f16* __restrict__ wfh, float* __restrict__ tab) {
  const int b = blockIdx.x;
  if (b == 0) {  // P table (in addition to this block's cvt share)
    const float w = 1.0f / (1.0f + expf(-mu[0]));
    for (int e = threadIdx.x; e < kNH * (kMAXL + 1); e += blockDim.x) {
      const int h = e / (kMAXL + 1);
      const int L = e - h * (kMAXL + 1);
      const float Lf = (float)L;
      float v;
      if (h < 4) {
        const float base = lam[h];
        const float mag = expf(Lf * logf(fabsf(base)));
        const float sgn = (base < 0.0f && (L & 1)) ? -1.0f : 1.0f;
        v = mag * sgn;
      } else if (h < 10) {
        const int s = h - 4;
        v = expf(Lf * logf(g1[s])) * sinf(th1[s] * Lf);
      } else {
        const int s = h - 10;
        v = expf(Lf * logf(g2[s])) * cosf(th2[s] * Lf);
      }
      tab[e] = w * v;
    }
    if (threadIdx.x == 0) tab[kNH * (kMAXL + 1)] = 1.0f - w;
  }

  const float* src;
  f16* dst;
  int n4, i0, nb;
  if (b < 2048) {  // x: 2M f16x4 groups over 2048 blocks
    src = x; dst = xh; n4 = kM * kD / 4; i0 = b; nb = 2048;
  } else {
    const int wsel = (b - 2048) >> 8;  // 0..3
    const int wb = (b - 2048) & 255;
    src = (wsel == 0) ? Wq : ((wsel == 1) ? Wk : ((wsel == 2) ? Wv : Wf));
    dst = (wsel == 0) ? wqh : ((wsel == 1) ? wkh : ((wsel == 2) ? wvh : wfh));
    n4 = kD * kD / 4; i0 = wb; nb = 256;
  }
  for (int i = i0 * 256 + threadIdx.x; i < n4; i += nb * 256) {
    fvec4 v = ((const fvec4*)src)[i];
    f16x4 o;
    o[0] = (f16)v[0]; o[1] = (f16)v[1]; o[2] = (f16)v[2]; o[3] = (f16)v[3];
    ((f16x4*)dst)[i] = o;
  }
}

// ---------------- V^T prefix column sums (R15) --------------------------------------
// Vpre[(bi*16+h)*16 + p][d] = sum_{j < p*128} V^T[h*64+d][bi*kT + j], f32.
// 64 blocks (one per bi,h) x 1024 threads (d = t>>4, tile p = t&15); each thread sums
// one 128-j tile, then 64 threads build the 16-entry prefix per d.
__global__ __launch_bounds__(1024) void vsum_kernel(const f16* __restrict__ Vt,
                                                    float* __restrict__ Vpre) {
  const int combo = blockIdx.x;  // bi*16 + h
  const int h = combo & 15;
  const int bi = combo >> 4;
  const int d = threadIdx.x >> 4;
  const int p = threadIdx.x & 15;
  const f16* src = Vt + (size_t)(h * 64 + d) * kM + (size_t)bi * kT + p * 128;
  float s = 0.f;
#pragma unroll
  for (int j = 0; j < 128; j += 8) {
    f16x8 v = *(const f16x8*)(src + j);
#pragma unroll
    for (int e = 0; e < 8; e++) s += (float)v[e];
  }
  __shared__ float ts[64][17];
  ts[d][p] = s;
  __syncthreads();
  if (p == 0) {
    float acc = 0.f;
    float* out = Vpre + (size_t)combo * 16 * 64 + d;
    for (int q = 0; q < 16; q++) {
      out[q * 64] = acc;  // prefix BEFORE tile q
      acc += ts[d][q];
    }
  }
}

// ---------------- C[m,n] = sum_k A[m,k]*B[n,k] (+bias) * oscale ----------------
// 128x128 tile, BK=32, 4 waves each 64x64, 16x16x32 f16 MFMA, register-prefetch staging.
template <typename OutT, bool BIAS_ROW>
__global__ __launch_bounds__(256, 3) void gemm_bt_kernel(
    const f16* __restrict__ A, const f16* __restrict__ B, const float* __restrict__ bias,
    OutT* __restrict__ C, int M, int N, int K, float oscale) {
  __shared__ f16 As[128][32];
  __shared__ f16 Bs[128][32];
  const int tid = threadIdx.x;
  const int lane = tid & 63;
  const int wave = tid >> 6;
  const int quad = lane >> 4;
  const int l16 = lane & 15;
  const int nb = N >> 7;
  const int bm = blockIdx.x / nb;
  const int bn = blockIdx.x - bm * nb;
  const int m0 = bm << 7;
  const int n0 = bn << 7;
  const int wm = (wave & 1) << 6;
  const int wn = (wave >> 1) << 6;

  const int srow = tid >> 2;        // 0..63
  const int scol = (tid & 3) << 3;  // 0,8,16,24
  const f16* Ap = A + (size_t)(m0 + srow) * K + scol;
  const f16* Bp = B + (size_t)(n0 + srow) * K + scol;
  const size_t rstep = (size_t)64 * K;

  f32x4 acc[4][4];
#pragma unroll
  for (int i = 0; i < 4; i++)
#pragma unroll
    for (int j = 0; j < 4; j++) acc[i][j] = (f32x4){0.f, 0.f, 0.f, 0.f};

  f16x8 ra0 = *(const f16x8*)(Ap);
  f16x8 ra1 = *(const f16x8*)(Ap + rstep);
  f16x8 rb0 = *(const f16x8*)(Bp);
  f16x8 rb1 = *(const f16x8*)(Bp + rstep);

  for (int k0 = 0; k0 < K; k0 += 32) {
    __syncthreads();
    *(f16x8*)&As[srow][scol] = ra0;
    *(f16x8*)&As[srow + 64][scol] = ra1;
    *(f16x8*)&Bs[srow][scol] = rb0;
    *(f16x8*)&Bs[srow + 64][scol] = rb1;
    __syncthreads();
    if (k0 + 32 < K) {  // prefetch next K-slab while computing
      ra0 = *(const f16x8*)(Ap + (k0 + 32));
      ra1 = *(const f16x8*)(Ap + rstep + (k0 + 32));
      rb0 = *(const f16x8*)(Bp + (k0 + 32));
      rb1 = *(const f16x8*)(Bp + rstep + (k0 + 32));
    }
    f16x8 af[4], bf[4];
#pragma unroll
    for (int i = 0; i < 4; i++) af[i] = *(const f16x8*)&As[wm + i * 16 + l16][quad * 8];
#pragma unroll
    for (int i = 0; i < 4; i++) bf[i] = *(const f16x8*)&Bs[wn + i * 16 + l16][quad * 8];
#pragma unroll
    for (int mi = 0; mi < 4; mi++)
#pragma unroll
      for (int ni = 0; ni < 4; ni++) acc[mi][ni] = MFMA16F16(af[mi], bf[ni], acc[mi][ni]);
  }

#pragma unroll
  for (int mi = 0; mi < 4; mi++) {
    const int rbase = m0 + wm + mi * 16 + quad * 4;
#pragma unroll
    for (int ni = 0; ni < 4; ni++) {
      const int gc = n0 + wn + ni * 16 + l16;
      const float bcol = BIAS_ROW ? 0.0f : bias[gc];
#pragma unroll
      for (int r = 0; r < 4; r++) {
        const int gr = rbase + r;
        float v = acc[mi][ni][r] + (BIAS_ROW ? bias[gr] : bcol);
        v *= oscale;
        C[(size_t)gr * N + gc] = (OutT)v;
      }
    }
  }
}

// ---------------- fused Q/K/V^T projection (one 1536-block dispatch) ----------------
__global__ __launch_bounds__(256, 3) void qkv_kernel(
    const f16* __restrict__ xh, const f16* __restrict__ wq, const f16* __restrict__ wk,
    const f16* __restrict__ wv, const float* __restrict__ bq, const float* __restrict__ bk,
    const float* __restrict__ bv, f16* __restrict__ Qp, f16* __restrict__ Kp,
    f16* __restrict__ Vt) {
  __shared__ f16 As[128][32];
  __shared__ f16 Bs[128][32];
  const int g = blockIdx.x >> 9;      // 0,1,2
  const int inner = blockIdx.x & 511; // 0..511
  const f16* A = (g == 2) ? wv : xh;
  const f16* B = (g == 0) ? wq : ((g == 1) ? wk : xh);
  const float* bias = (g == 0) ? bq : ((g == 1) ? bk : bv);
  f16* C = (g == 0) ? Qp : ((g == 1) ? Kp : Vt);
  const int N = (g == 2) ? kM : kD;
  const int K = kD;
  const float oscale = (g == 0) ? kLOG2E : 1.0f;
  const bool bias_row = (g == 2);
  const int nbs = (g == 2) ? 6 : 3;  // log2(N/128)

  const int tid = threadIdx.x;
  const int lane = tid & 63;
  const int wave = tid >> 6;
  const int quad = lane >> 4;
  const int l16 = lane & 15;
  const int bm = inner >> nbs;
  const int bn = inner & ((1 << nbs) - 1);
  const int m0 = bm << 7;
  const int n0 = bn << 7;
  const int wm = (wave & 1) << 6;
  const int wn = (wave >> 1) << 6;

  const int srow = tid >> 2;
  const int scol = (tid & 3) << 3;
  const f16* Ap = A + (size_t)(m0 + srow) * K + scol;
  const f16* Bp = B + (size_t)(n0 + srow) * K + scol;
  const size_t rstep = (size_t)64 * K;

  f32x4 acc[4][4];
#pragma unroll
  for (int i = 0; i < 4; i++)
#pragma unroll
    for (int j = 0; j < 4; j++) acc[i][j] = (f32x4){0.f, 0.f, 0.f, 0.f};

  f16x8 ra0 = *(const f16x8*)(Ap);
  f16x8 ra1 = *(const f16x8*)(Ap + rstep);
  f16x8 rb0 = *(const f16x8*)(Bp);
  f16x8 rb1 = *(const f16x8*)(Bp + rstep);

  for (int k0 = 0; k0 < K; k0 += 32) {
    __syncthreads();
    *(f16x8*)&As[srow][scol] = ra0;
    *(f16x8*)&As[srow + 64][scol] = ra1;
    *(f16x8*)&Bs[srow][scol] = rb0;
    *(f16x8*)&Bs[srow + 64][scol] = rb1;
    __syncthreads();
    if (k0 + 32 < K) {
      ra0 = *(const f16x8*)(Ap + (k0 + 32));
      ra1 = *(const f16x8*)(Ap + rstep + (k0 + 32));
      rb0 = *(const f16x8*)(Bp + (k0 + 32));
      rb1 = *(const f16x8*)(Bp + rstep + (k0 + 32));
    }
    f16x8 af[4], bf[4];
#pragma unroll
    for (int i = 0; i < 4; i++) af[i] = *(const f16x8*)&As[wm + i * 16 + l16][quad * 8];
#pragma unroll
    for (int i = 0; i < 4; i++) bf[i] = *(const f16x8*)&Bs[wn + i * 16 + l16][quad * 8];
#pragma unroll
    for (int mi = 0; mi < 4; mi++)
#pragma unroll
      for (int ni = 0; ni < 4; ni++) acc[mi][ni] = MFMA16F16(af[mi], bf[ni], acc[mi][ni]);
  }

#pragma unroll
  for (int mi = 0; mi < 4; mi++) {
    const int rbase = m0 + wm + mi * 16 + quad * 4;
#pragma unroll
    for (int ni = 0; ni < 4; ni++) {
      const int gc = n0 + wn + ni * 16 + l16;
      const float bcol = bias_row ? 0.0f : bias[gc];
#pragma unroll
      for (int r = 0; r < 4; r++) {
        const int gr = rbase + r;
        float v = acc[mi][ni][r] + (bias_row ? bias[gr] : bcol);
        v *= oscale;
        C[(size_t)gr * N + gc] = (f16)v;
      }
    }
  }
}

// ---------------- fused attention + positional blend, 32x32 MFMA / O^T form ----------
// R13 structure + R15: the const-positional region (tiles j0 <= qblk-256, identical for
// all 4 waves = first qt-1 tiles) is q-independent: Opc = tab100 * ColSum(V^T prefix).
// Replaced the in-loop Opc MFMA block (up to 16 MFMA/late tile, ~17% of MFMA work) with
// 32 scalar reads from the precomputed Vpre table; frees 32 accumulator VGPRs.
// MEASURED constraints (do not re-try):
//  - R5: 4 blocks/CU -> L2 thrash, HBM 4.4x. L2 residency > wave residency.
//  - R7: T14 reg-prefetch of next K/V tile -> 2-tile footprint -> L2 spill, HBM 2.5x.
//  - R8: s_setprio: +6 us (4-wave lockstep blocks starve VALU waves).
//  - R10: merged-128j softmax (s[4] live) -> reg-budget overflow -> scratch spills.
//  - R14: band folded into main loop: traffic -15% but attn +4 us (in-loop code wrecks
//    scheduling when latency-bound). Band stays in the epilogue.
__global__ __launch_bounds__(256, 3) void attn_kernel(
    const f16* __restrict__ Qh, const f16* __restrict__ Kh, const f16* __restrict__ Vt,
    const float* __restrict__ tabg, const float* __restrict__ Vpre, f16* __restrict__ Pb) {
  __shared__ f16 Ks[128][68];   // K tile [j][d], +4 pad: row stride 34 dw -> 2-way banks
  __shared__ f16 Vs[64][132];   // V^T tile [d][j], +4 pad: row stride 66 dw -> 2-way
  __shared__ float tab_s[101];

  const int tid = threadIdx.x;
  const int lane = tid & 63;
  const int wave = tid >> 6;
  const int l31 = lane & 31;
  const int hi = lane >> 5;
  const int hi8 = hi * 8;
  // XCD-affinity decode
  const int xcd = blockIdx.x & 7;
  const int rest = blockIdx.x >> 3;         // 0..127
  const int qt = rest & 15;
  const int combo = (rest >> 4) * 8 + xcd;  // 0..63 == bi*16 + h
  const int h = combo & 15;
  const int bi = combo >> 4;

  if (tid < 101) tab_s[tid] = tabg[h * 101 + tid];
  const float one_m_w = tabg[kNH * 101];
  const float tab100f = tabg[h * 101 + kMAXL];

  const int qblk = qt * 128;
  const int qw0 = qblk + wave * 32;  // wave's q base (32 q per wave)
  const int qg = qw0 + l31;          // this lane's q (t-local)
  const size_t bt0 = (size_t)bi * kT;

  // Q^T B-fragments: B[k=d][col=q], lane col=q=l31, k = hi*8+e, d = kc*16+hi*8+e
  f16x8 qf[4];
#pragma unroll
  for (int kc = 0; kc < 4; kc++)
    qf[kc] = *(const f16x8*)(Qh + (bt0 + qg) * kD + h * 64 + kc * 16 + hi8);

  f32x16 Oat[2];  // O^T accumulators: row=d (dt*32 + pattern), col=q
  f32x16 Lacc;    // softmax denominator accumulator (only [0] meaningful)
#pragma unroll
  for (int dt = 0; dt < 2; dt++)
#pragma unroll
    for (int r = 0; r < 16; r++) Oat[dt][r] = 0.f;
#pragma unroll
  for (int r = 0; r < 16; r++) Lacc[r] = 0.f;
  float mrow = -INFINITY;

  const int sr8 = tid >> 3, sp8 = tid & 7;
  const int sr16 = tid >> 4, sp16 = tid & 15;

  f16x8 ones;  // all-ones A fragment for the denominator MFMA
#pragma unroll
  for (int ii = 0; ii < 8; ii++) ones[ii] = (f16)1.0f;

  for (int j0 = 0; j0 < kT; j0 += 128) {
    __syncthreads();
    // stage K tile [j][d]
#pragma unroll
    for (int u = 0; u < 4; u++) {
      const int jr = sr8 + u * 32;
      *(f16x8*)&Ks[jr][sp8 * 8] = *(const f16x8*)(Kh + (bt0 + j0 + jr) * kD + h * 64 + sp8 * 8);
    }
    // stage V^T tile [d][j]
#pragma unroll
    for (int u = 0; u < 4; u++) {
      const int d = sr16 + u * 16;
      *(f16x8*)&Vs[d][sp16 * 8] =
          *(const f16x8*)(Vt + (size_t)(h * 64 + d) * kM + bt0 + j0 + sp16 * 8);
    }
    __syncthreads();

#pragma unroll
    for (int c = 0; c < 2; c++) {  // 64-j chunks
      // S^T = K Q^T : two 32-j tiles, contraction over d in 4 chunks of 16
      f32x16 s[2];
#pragma unroll
      for (int jt = 0; jt < 2; jt++)
#pragma unroll
        for (int r = 0; r < 16; r++) s[jt][r] = 0.f;
#pragma unroll
      for (int kc = 0; kc < 4; kc++) {
        f16x8 ka = *(const f16x8*)&Ks[c * 64 + l31][kc * 16 + hi8];
        f16x8 kb = *(const f16x8*)&Ks[c * 64 + 32 + l31][kc * 16 + hi8];
        s[0] = MFMA32F16(ka, qf[kc], s[0]);
        s[1] = MFMA32F16(kb, qf[kc], s[1]);
      }

      // online softmax with defer-max: lane owns column q; rows split lane<->lane^32
      float mx = s[0][0];
#pragma unroll
      for (int jt = 0; jt < 2; jt++)
#pragma unroll
        for (int r = 0; r < 16; r++) mx = fmaxf(mx, s[jt][r]);
      mx = fmaxf(mx, __shfl_xor(mx, 32));
      if (!__all(mx <= mrow + 8.0f)) {  // raise running max only when needed
        const float mnew = fmaxf(mrow, mx);
        const float al = __builtin_amdgcn_exp2f(mrow - mnew);
        mrow = mnew;
#pragma unroll
        for (int dt = 0; dt < 2; dt++)
#pragma unroll
          for (int r = 0; r < 16; r++) Oat[dt][r] *= al;
        Lacc[0] *= al;
      }

#pragma unroll
      for (int jt = 0; jt < 2; jt++) {
        // exp2 + pack: w[k] covers j-row pairs (2k,2k+1) of this jt tile's lane half
        unsigned w[8];
#pragma unroll
        for (int k = 0; k < 8; k++) {
          const float e0 = __builtin_amdgcn_exp2f(s[jt][2 * k] - mrow);
          const float e1 = __builtin_amdgcn_exp2f(s[jt][2 * k + 1] - mrow);
          w[k] = pk_f16(e0, e1);
        }
        // P^T B-fragments via permlane32_swap:
        //  even 16-j half: words = {sw(w0,w2).x, sw(w1,w3).x, sw(w0,w2).y, sw(w1,w3).y}
        //  odd  16-j half: same with w4..w7
        i32x2 a0 = pl32swap(w[0], w[2]);
        i32x2 a1 = pl32swap(w[1], w[3]);
        i32x2 b0 = pl32swap(w[4], w[6]);
        i32x2 b1 = pl32swap(w[5], w[7]);
        u32x4 ue = {(unsigned)a0.x, (unsigned)a1.x, (unsigned)a0.y, (unsigned)a1.y};
        u32x4 uo = {(unsigned)b0.x, (unsigned)b1.x, (unsigned)b0.y, (unsigned)b1.y};
        const f16x8 fe = __builtin_bit_cast(f16x8, ue);
        const f16x8 fo = __builtin_bit_cast(f16x8, uo);
        // O^T += V^T @ P^T over this jt tile's two 16-j chunks; denominator via ones@P^T
#pragma unroll
        for (int dt = 0; dt < 2; dt++) {
          f16x8 ve = *(const f16x8*)&Vs[dt * 32 + l31][c * 64 + jt * 32 + hi8];
          Oat[dt] = MFMA32F16(ve, fe, Oat[dt]);
        }
        Lacc = MFMA32F16(ones, fe, Lacc);
#pragma unroll
        for (int dt = 0; dt < 2; dt++) {
          f16x8 vo = *(const f16x8*)&Vs[dt * 32 + l31][c * 64 + jt * 32 + 16 + hi8];
          Oat[dt] = MFMA32F16(vo, fo, Oat[dt]);
        }
        Lacc = MFMA32F16(ones, fo, Lacc);
      }
    }
  }

  // scale attention by (1-w)/l (lane-uniform!) and add const-positional region from the
  // precomputed V^T prefix sums: tiles j0 <= qblk-256 == first (qt-1) tiles, identical
  // for all waves. Vpre[p] = colsum over first p tiles; p = max(qt-1, 0) (Vpre[0] = 0).
  {
    const float inv = one_m_w / Lacc[0];
    const int pidx = (qt >= 1) ? (qt - 1) : 0;
    const float* vp = Vpre + ((size_t)(bi * 16 + h) * 16 + pidx) * 64;
#pragma unroll
    for (int dt = 0; dt < 2; dt++)
#pragma unroll
      for (int r = 0; r < 16; r++) {
        const int dd = dt * 32 + (r & 3) + 8 * (r >> 2) + 4 * hi;
        Oat[dt][r] = Oat[dt][r] * inv + tab100f * vp[dd];
      }
  }

  // near-diagonal positional band: restage the two boundary V tiles, table B-fragments
#pragma unroll
  for (int tb = 0; tb < 2; tb++) {
    const int jb = qblk - 128 + tb * 128;  // block-uniform
    if (jb >= 0) {
      __syncthreads();
#pragma unroll
      for (int u = 0; u < 4; u++) {
        const int d = sr16 + u * 16;
        *(f16x8*)&Vs[d][sp16 * 8] =
            *(const f16x8*)(Vt + (size_t)(h * 64 + d) * kM + bt0 + jb + sp16 * 8);
      }
      __syncthreads();
#pragma unroll
      for (int jc = 0; jc < 8; jc++) {
        f16x8 wf;
#pragma unroll
        for (int e = 0; e < 8; e++) {
          const int j = jb + jc * 16 + hi8 + e;
          const int dlt = qg - j;
          float pv = 0.0f;
          if (dlt > 0) pv = tab_s[dlt > kMAXL ? kMAXL : dlt];
          wf[e] = (f16)pv;
        }
#pragma unroll
        for (int dt = 0; dt < 2; dt++) {
          f16x8 vf = *(const f16x8*)&Vs[dt * 32 + l31][jc * 16 + hi8];
          Oat[dt] = MFMA32F16(vf, wf, Oat[dt]);
        }
      }
    }
  }

  // epilogue: un-transpose O^T -> Pb[q][d] via per-wave LDS scratch (reuses Ks; all
  // waves passed the band barriers, so Ks is dead). Wave w owns Ks rows [32w,32w+32).
  {
    f16* sw = &Ks[wave * 32][0];  // viewed as [32 q][68]
#pragma unroll
    for (int dt = 0; dt < 2; dt++)
#pragma unroll
      for (int r = 0; r < 16; r++) {
        const int d = dt * 32 + (r & 3) + 8 * (r >> 2) + 4 * hi;
        sw[l31 * 68 + d] = (f16)Oat[dt][r];
      }
    // in-wave LDS write->read ordering handled by compiler (lgkmcnt)
#pragma unroll
    for (int u = 0; u < 4; u++) {
      const int qr = lane >> 1;
      const int c0 = (lane & 1) * 32 + u * 8;
      f16x8 ofr = *(const f16x8*)&sw[qr * 68 + c0];
      *(f16x8*)(Pb + (bt0 + qw0 + qr) * kD + h * 64 + c0) = ofr;
    }
  }
}

extern "C" void kernel_launch(void* const* d_in, const int* in_sizes, int n_in, void* d_out,
                              int out_size, void* d_ws, size_t ws_size, hipStream_t stream) {
  const float* x = (const float*)d_in[0];
  const float* mu = (const float*)d_in[1];
  const float* lam = (const float*)d_in[2];
  const float* g1 = (const float*)d_in[3];
  const float* g2 = (const float*)d_in[4];
  const float* th1 = (const float*)d_in[5];
  const float* th2 = (const float*)d_in[6];
  const float* Wq = (const float*)d_in[7];
  const float* bq = (const float*)d_in[8];
  const float* Wk = (const float*)d_in[9];
  const float* bk = (const float*)d_in[10];
  const float* Wv = (const float*)d_in[11];
  const float* bv = (const float*)d_in[12];
  const float* Wf = (const float*)d_in[13];
  const float* bf = (const float*)d_in[14];

  if (ws_size < WS_NEED) return;  // cannot run without scratch

  char* ws = (char*)d_ws;
  float* tab = (float*)(ws + OFF_TAB);
  f16* xh = (f16*)(ws + OFF_XH);
  f16* wqh = (f16*)(ws + OFF_WQ);
  f16* wkh = (f16*)(ws + OFF_WK);
  f16* wvh = (f16*)(ws + OFF_WV);
  f16* wfh = (f16*)(ws + OFF_WF);
  f16* Qp = (f16*)(ws + OFF_Q);
  f16* Kp = (f16*)(ws + OFF_K);
  f16* Vtp = (f16*)(ws + OFF_V);
  f16* Pbp = (f16*)(ws + OFF_P);
  float* Vpre = (float*)(ws + OFF_VPRE);  // aliases xh (dead after qkv)

  // fused preprocessing: tab + all fp32->fp16 converts in ONE dispatch
  pre_kernel<<<3072, 256, 0, stream>>>(x, Wq, Wk, Wv, Wf, mu, lam, g1, g2, th1, th2, xh, wqh,
                                       wkh, wvh, wfh, tab);

  // fused Q/K/V^T projections (Q scaled by log2(e) after bias for exp2 softmax).
  qkv_kernel<<<1536, 256, 0, stream>>>(xh, wqh, wkh, wvh, bq, bk, bv, Qp, Kp, Vtp);

  // V^T prefix column sums for the const-positional region (writes over dead xh).
  vsum_kernel<<<64, 1024, 0, stream>>>(Vtp, Vpre);

  attn_kernel<<<1024, 256, 0, stream>>>(Qp, Kp, Vtp, tab, Vpre, Pbp);

  gemm_bt_kernel<float, false><<<512, 256, 0, stream>>>(Pbp, wfh, bf, (float*)d_out, kM, kD, kD,
                                                        1.0f);
}

// Round 16
// 331.727 us; speedup vs baseline: 1.0987x; 1.0439x over previous
//
#include <hip/hip_runtime.h>
#include <math.h>
#include <stdint.h>
#include <stddef.h>

typedef _Float16 f16;
typedef _Float16 f16x8 __attribute__((ext_vector_type(8)));
typedef _Float16 f16x4 __attribute__((ext_vector_type(4)));
typedef __fp16 fp16x2 __attribute__((ext_vector_type(2)));
typedef float f32x4 __attribute__((ext_vector_type(4)));
typedef float f32x16 __attribute__((ext_vector_type(16)));
typedef float fvec4 __attribute__((ext_vector_type(4)));
typedef unsigned int u32x4 __attribute__((ext_vector_type(4)));
typedef int i32x2 __attribute__((ext_vector_type(2)));

#define MFMA16F16(a, b, c) __builtin_amdgcn_mfma_f32_16x16x32_f16((a), (b), (c), 0, 0, 0)
#define MFMA32F16(a, b, c) __builtin_amdgcn_mfma_f32_32x32x16_f16((a), (b), (c), 0, 0, 0)

static constexpr int kT = 2048;
static constexpr int kB = 4;
static constexpr int kD = 1024;
static constexpr int kNH = 16;
static constexpr int kM = kB * kT;  // 8192
static constexpr int kMAXL = 100;
static constexpr float kLOG2E = 1.4426950408889634f;

// ---------------- workspace layout (bytes) ----------------
static constexpr size_t SZ_XH = (size_t)kM * kD * 2;  // 16 MB fp16
static constexpr size_t SZ_W = (size_t)kD * kD * 2;   // 2 MB fp16
static constexpr size_t OFF_TAB = 0;                  // 16*101 floats + (1-w)
static constexpr size_t OFF_XH = 8192;
static constexpr size_t OFF_WQ = OFF_XH + SZ_XH;
static constexpr size_t OFF_WK = OFF_WQ + SZ_W;
static constexpr size_t OFF_WV = OFF_WK + SZ_W;
static constexpr size_t OFF_WF = OFF_WV + SZ_W;
static constexpr size_t OFF_Q = OFF_WF + SZ_W;
static constexpr size_t OFF_K = OFF_Q + SZ_XH;
static constexpr size_t OFF_V = OFF_K + SZ_XH;   // holds V^T [1024][8192]
static constexpr size_t OFF_P = OFF_V + SZ_XH;   // blended (blend@V) fp16
static constexpr size_t WS_NEED = OFF_P + SZ_XH; // ~92 MB
// V^T prefix-column-sum table (64 KB of floats) ALIASES xh: xh is dead after qkv, and
// vsum runs after qkv. Vpre[(bi*16+h)*16 + p][d] = sum_{j < p*128} V^T[d][j] (f32).
static constexpr size_t OFF_VPRE = OFF_XH;

__device__ __forceinline__ unsigned int pk_f16(float a, float b) {
  fp16x2 h = __builtin_amdgcn_cvt_pkrtz(a, b);
  return __builtin_bit_cast(unsigned int, h);
}

// v_permlane32_swap_b32: ret.x = [a(0:31) | b(0:31)], ret.y = [a(32:63) | b(32:63)]
__device__ __forceinline__ i32x2 pl32swap(unsigned a, unsigned b) {
  return __builtin_amdgcn_permlane32_swap((int)a, (int)b, false, false);
}

// ---------------- fused preprocessing: tab + all 5 fp32->fp16 converts --------------
// One dispatch replaces 6 (R13 win, -13.5 us): blocks 0..2047 convert x (grid-stride);
// blocks 2048..3071 convert the 4 weight matrices; block 0 also computes the P table.
__global__ void pre_kernel(const float* __restrict__ x, const float* __restrict__ Wq,
                           const float* __restrict__ Wk, const float* __restrict__ Wv,
                           const float* __restrict__ Wf, const float* __restrict__ mu,
                           const float* __restrict__ lam, const float* __restrict__ g1,
                           const float* __restrict__ g2, const float* __restrict__ th1,
                           const float* __restrict__ th2, f16* __restrict__ xh,
                           f16* __restrict__ wqh, f16* __restrict__ wkh, f16* __restrict__ wvh,
                           f16* __restrict__ wfh, float* __restrict__ tab) {
  const int b = blockIdx.x;
  if (b == 0) {  // P table (in addition to this block's cvt share)
    const float w = 1.0f / (1.0f + expf(-mu[0]));
    for (int e = threadIdx.x; e < kNH * (kMAXL + 1); e += blockDim.x) {
      const int h = e / (kMAXL + 1);
      const int L = e - h * (kMAXL + 1);
      const float Lf = (float)L;
      float v;
      if (h < 4) {
        const float base = lam[h];
        const float mag = expf(Lf * logf(fabsf(base)));
        const float sgn = (base < 0.0f && (L & 1)) ? -1.0f : 1.0f;
        v = mag * sgn;
      } else if (h < 10) {
        const int s = h - 4;
        v = expf(Lf * logf(g1[s])) * sinf(th1[s] * Lf);
      } else {
        const int s = h - 10;
        v = expf(Lf * logf(g2[s])) * cosf(th2[s] * Lf);
      }
      tab[e] = w * v;
    }
    if (threadIdx.x == 0) tab[kNH * (kMAXL + 1)] = 1.0f - w;
  }

  const float* src;
  f16* dst;
  int n4, i0, nb;
  if (b < 2048) {  // x: 2M f16x4 groups over 2048 blocks
    src = x; dst = xh; n4 = kM * kD / 4; i0 = b; nb = 2048;
  } else {
    const int wsel = (b - 2048) >> 8;  // 0..3
    const int wb = (b - 2048) & 255;
    src = (wsel == 0) ? Wq : ((wsel == 1) ? Wk : ((wsel == 2) ? Wv : Wf));
    dst = (wsel == 0) ? wqh : ((wsel == 1) ? wkh : ((wsel == 2) ? wvh : wfh));
    n4 = kD * kD / 4; i0 = wb; nb = 256;
  }
  for (int i = i0 * 256 + threadIdx.x; i < n4; i += nb * 256) {
    fvec4 v = ((const fvec4*)src)[i];
    f16x4 o;
    o[0] = (f16)v[0]; o[1] = (f16)v[1]; o[2] = (f16)v[2]; o[3] = (f16)v[3];
    ((f16x4*)dst)[i] = o;
  }
}

// ---------------- V^T prefix column sums (R16: fully parallel) ----------------------
// Vpre[(bi*16+h)*16 + p][d] = sum_{j < p*128} V^T[h*64+d][bi*kT + j], f32.
// R15's version was 64 blocks (1/4 CU occupancy on a 16 MB read, ~10-15 us). Now:
// 256 blocks x 1024 threads (1 block/CU): combo = b>>2, d-slice = b&3; thread =
// (d_local, p, quarter); each thread sums 32 j's, 4-lane shfl reduce, 16 threads/block
// do the 16-entry prefix. Full-BW 16 MB read ~= 3 us.
__global__ __launch_bounds__(1024) void vsum_kernel(const f16* __restrict__ Vt,
                                                    float* __restrict__ Vpre) {
  const int combo = blockIdx.x >> 2;  // bi*16 + h
  const int dg = blockIdx.x & 3;
  const int h = combo & 15;
  const int bi = combo >> 4;
  const int dl = threadIdx.x >> 6;        // 0..15
  const int d = dg * 16 + dl;             // 0..63
  const int p = (threadIdx.x >> 2) & 15;  // tile index
  const int qq = threadIdx.x & 3;         // quarter of the 128-j tile
  const f16* src = Vt + (size_t)(h * 64 + d) * kM + (size_t)bi * kT + p * 128 + qq * 32;
  float s = 0.f;
#pragma unroll
  for (int j = 0; j < 32; j += 8) {
    f16x8 v = *(const f16x8*)(src + j);
#pragma unroll
    for (int e = 0; e < 8; e++) s += (float)v[e];
  }
  s += __shfl_xor(s, 1);
  s += __shfl_xor(s, 2);
  __shared__ float ts[16][17];
  if (qq == 0) ts[dl][p] = s;
  __syncthreads();
  if (qq == 0 && p == 0) {
    float acc = 0.f;
    float* out = Vpre + (size_t)combo * 16 * 64 + d;
    for (int q = 0; q < 16; q++) {
      out[q * 64] = acc;  // prefix BEFORE tile q
      acc += ts[dl][q];
    }
  }
}

// ---------------- C[m,n] = sum_k A[m,k]*B[n,k] (+bias) * oscale ----------------
// 128x128 tile, BK=32, 4 waves each 64x64, 16x16x32 f16 MFMA, register-prefetch staging.
template <typename OutT, bool BIAS_ROW>
__global__ __launch_bounds__(256, 3) void gemm_bt_kernel(
    const f16* __restrict__ A, const f16* __restrict__ B, const float* __restrict__ bias,
    OutT* __restrict__ C, int M, int N, int K, float oscale) {
  __shared__ f16 As[128][32];
  __shared__ f16 Bs[128][32];
  const int tid = threadIdx.x;
  const int lane = tid & 63;
  const int wave = tid >> 6;
  const int quad = lane >> 4;
  const int l16 = lane & 15;
  const int nb = N >> 7;
  const int bm = blockIdx.x / nb;
  const int bn = blockIdx.x - bm * nb;
  const int m0 = bm << 7;
  const int n0 = bn << 7;
  const int wm = (wave & 1) << 6;
  const int wn = (wave >> 1) << 6;

  const int srow = tid >> 2;        // 0..63
  const int scol = (tid & 3) << 3;  // 0,8,16,24
  const f16* Ap = A + (size_t)(m0 + srow) * K + scol;
  const f16* Bp = B + (size_t)(n0 + srow) * K + scol;
  const size_t rstep = (size_t)64 * K;

  f32x4 acc[4][4];
#pragma unroll
  for (int i = 0; i < 4; i++)
#pragma unroll
    for (int j = 0; j < 4; j++) acc[i][j] = (f32x4){0.f, 0.f, 0.f, 0.f};

  f16x8 ra0 = *(const f16x8*)(Ap);
  f16x8 ra1 = *(const f16x8*)(Ap + rstep);
  f16x8 rb0 = *(const f16x8*)(Bp);
  f16x8 rb1 = *(const f16x8*)(Bp + rstep);

  for (int k0 = 0; k0 < K; k0 += 32) {
    __syncthreads();
    *(f16x8*)&As[srow][scol] = ra0;
    *(f16x8*)&As[srow + 64][scol] = ra1;
    *(f16x8*)&Bs[srow][scol] = rb0;
    *(f16x8*)&Bs[srow + 64][scol] = rb1;
    __syncthreads();
    if (k0 + 32 < K) {  // prefetch next K-slab while computing
      ra0 = *(const f16x8*)(Ap + (k0 + 32));
      ra1 = *(const f16x8*)(Ap + rstep + (k0 + 32));
      rb0 = *(const f16x8*)(Bp + (k0 + 32));
      rb1 = *(const f16x8*)(Bp + rstep + (k0 + 32));
    }
    f16x8 af[4], bf[4];
#pragma unroll
    for (int i = 0; i < 4; i++) af[i] = *(const f16x8*)&As[wm + i * 16 + l16][quad * 8];
#pragma unroll
    for (int i = 0; i < 4; i++) bf[i] = *(const f16x8*)&Bs[wn + i * 16 + l16][quad * 8];
#pragma unroll
    for (int mi = 0; mi < 4; mi++)
#pragma unroll
      for (int ni = 0; ni < 4; ni++) acc[mi][ni] = MFMA16F16(af[mi], bf[ni], acc[mi][ni]);
  }

#pragma unroll
  for (int mi = 0; mi < 4; mi++) {
    const int rbase = m0 + wm + mi * 16 + quad * 4;
#pragma unroll
    for (int ni = 0; ni < 4; ni++) {
      const int gc = n0 + wn + ni * 16 + l16;
      const float bcol = BIAS_ROW ? 0.0f : bias[gc];
#pragma unroll
      for (int r = 0; r < 4; r++) {
        const int gr = rbase + r;
        float v = acc[mi][ni][r] + (BIAS_ROW ? bias[gr] : bcol);
        v *= oscale;
        C[(size_t)gr * N + gc] = (OutT)v;
      }
    }
  }
}

// ---------------- fused Q/K/V^T projection (one 1536-block dispatch) ----------------
__global__ __launch_bounds__(256, 3) void qkv_kernel(
    const f16* __restrict__ xh, const f16* __restrict__ wq, const f16* __restrict__ wk,
    const f16* __restrict__ wv, const float* __restrict__ bq, const float* __restrict__ bk,
    const float* __restrict__ bv, f16* __restrict__ Qp, f16* __restrict__ Kp,
    f16* __restrict__ Vt) {
  __shared__ f16 As[128][32];
  __shared__ f16 Bs[128][32];
  const int g = blockIdx.x >> 9;      // 0,1,2
  const int inner = blockIdx.x & 511; // 0..511
  const f16* A = (g == 2) ? wv : xh;
  const f16* B = (g == 0) ? wq : ((g == 1) ? wk : xh);
  const float* bias = (g == 0) ? bq : ((g == 1) ? bk : bv);
  f16* C = (g == 0) ? Qp : ((g == 1) ? Kp : Vt);
  const int N = (g == 2) ? kM : kD;
  const int K = kD;
  const float oscale = (g == 0) ? kLOG2E : 1.0f;
  const bool bias_row = (g == 2);
  const int nbs = (g == 2) ? 6 : 3;  // log2(N/128)

  const int tid = threadIdx.x;
  const int lane = tid & 63;
  const int wave = tid >> 6;
  const int quad = lane >> 4;
  const int l16 = lane & 15;
  const int bm = inner >> nbs;
  const int bn = inner & ((1 << nbs) - 1);
  const int m0 = bm << 7;
  const int n0 = bn << 7;
  const int wm = (wave & 1) << 6;
  const int wn = (wave >> 1) << 6;

  const int srow = tid >> 2;
  const int scol = (tid & 3) << 3;
  const f16* Ap = A + (size_t)(m0 + srow) * K + scol;
  const f16* Bp = B + (size_t)(n0 + srow) * K + scol;
  const size_t rstep = (size_t)64 * K;

  f32x4 acc[4][4];
#pragma unroll
  for (int i = 0; i < 4; i++)
#pragma unroll
    for (int j = 0; j < 4; j++) acc[i][j] = (f32x4){0.f, 0.f, 0.f, 0.f};

  f16x8 ra0 = *(const f16x8*)(Ap);
  f16x8 ra1 = *(const f16x8*)(Ap + rstep);
  f16x8 rb0 = *(const f16x8*)(Bp);
  f16x8 rb1 = *(const f16x8*)(Bp + rstep);

  for (int k0 = 0; k0 < K; k0 += 32) {
    __syncthreads();
    *(f16x8*)&As[srow][scol] = ra0;
    *(f16x8*)&As[srow + 64][scol] = ra1;
    *(f16x8*)&Bs[srow][scol] = rb0;
    *(f16x8*)&Bs[srow + 64][scol] = rb1;
    __syncthreads();
    if (k0 + 32 < K) {
      ra0 = *(const f16x8*)(Ap + (k0 + 32));
      ra1 = *(const f16x8*)(Ap + rstep + (k0 + 32));
      rb0 = *(const f16x8*)(Bp + (k0 + 32));
      rb1 = *(const f16x8*)(Bp + rstep + (k0 + 32));
    }
    f16x8 af[4], bf[4];
#pragma unroll
    for (int i = 0; i < 4; i++) af[i] = *(const f16x8*)&As[wm + i * 16 + l16][quad * 8];
#pragma unroll
    for (int i = 0; i < 4; i++) bf[i] = *(const f16x8*)&Bs[wn + i * 16 + l16][quad * 8];
#pragma unroll
    for (int mi = 0; mi < 4; mi++)
#pragma unroll
      for (int ni = 0; ni < 4; ni++) acc[mi][ni] = MFMA16F16(af[mi], bf[ni], acc[mi][ni]);
  }

#pragma unroll
  for (int mi = 0; mi < 4; mi++) {
    const int rbase = m0 + wm + mi * 16 + quad * 4;
#pragma unroll
    for (int ni = 0; ni < 4; ni++) {
      const int gc = n0 + wn + ni * 16 + l16;
      const float bcol = bias_row ? 0.0f : bias[gc];
#pragma unroll
      for (int r = 0; r < 4; r++) {
        const int gr = rbase + r;
        float v = acc[mi][ni][r] + (bias_row ? bias[gr] : bcol);
        v *= oscale;
        C[(size_t)gr * N + gc] = (f16)v;
      }
    }
  }
}

// ---------------- fused attention + positional blend, 32x32 MFMA / O^T form ----------
// R15 form (attn 121.4 us): const-positional region replaced by precomputed V^T prefix
// sums (q-independent) — the Opc MFMAs were on the critical path (-24 us).
// S^T = K@Q^T via mfma_f32_32x32x16 (lane owns one q-column); defer-max softmax (THR=8);
// O^T = V^T @ P^T via permlane32_swap fragments; denominator via ones@P^T MFMA;
// band epilogue; LDS un-transpose.
// MEASURED constraints (do not re-try):
//  - R5: 4 blocks/CU -> L2 thrash, HBM 4.4x. L2 residency > wave residency.
//  - R7: T14 reg-prefetch of next K/V tile -> 2-tile footprint -> L2 spill, HBM 2.5x.
//  - R8: s_setprio: +6 us (4-wave lockstep blocks starve VALU waves).
//  - R10: merged-128j softmax (s[4] live) -> reg-budget overflow -> scratch spills.
//  - R14: band folded into main loop: traffic -15% but attn +4 us. Band stays epilogue.
__global__ __launch_bounds__(256, 3) void attn_kernel(
    const f16* __restrict__ Qh, const f16* __restrict__ Kh, const f16* __restrict__ Vt,
    const float* __restrict__ tabg, const float* __restrict__ Vpre, f16* __restrict__ Pb) {
  __shared__ f16 Ks[128][68];   // K tile [j][d], +4 pad: row stride 34 dw -> 2-way banks
  __shared__ f16 Vs[64][132];   // V^T tile [d][j], +4 pad: row stride 66 dw -> 2-way
  __shared__ float tab_s[101];

  const int tid = threadIdx.x;
  const int lane = tid & 63;
  const int wave = tid >> 6;
  const int l31 = lane & 31;
  const int hi = lane >> 5;
  const int hi8 = hi * 8;
  // XCD-affinity decode
  const int xcd = blockIdx.x & 7;
  const int rest = blockIdx.x >> 3;         // 0..127
  const int qt = rest & 15;
  const int combo = (rest >> 4) * 8 + xcd;  // 0..63 == bi*16 + h
  const int h = combo & 15;
  const int bi = combo >> 4;

  if (tid < 101) tab_s[tid] = tabg[h * 101 + tid];
  const float one_m_w = tabg[kNH * 101];
  const float tab100f = tabg[h * 101 + kMAXL];

  const int qblk = qt * 128;
  const int qw0 = qblk + wave * 32;  // wave's q base (32 q per wave)
  const int qg = qw0 + l31;          // this lane's q (t-local)
  const size_t bt0 = (size_t)bi * kT;

  // Q^T B-fragments: B[k=d][col=q], lane col=q=l31, k = hi*8+e, d = kc*16+hi*8+e
  f16x8 qf[4];
#pragma unroll
  for (int kc = 0; kc < 4; kc++)
    qf[kc] = *(const f16x8*)(Qh + (bt0 + qg) * kD + h * 64 + kc * 16 + hi8);

  f32x16 Oat[2];  // O^T accumulators: row=d (dt*32 + pattern), col=q
  f32x16 Lacc;    // softmax denominator accumulator (only [0] meaningful)
#pragma unroll
  for (int dt = 0; dt < 2; dt++)
#pragma unroll
    for (int r = 0; r < 16; r++) Oat[dt][r] = 0.f;
#pragma unroll
  for (int r = 0; r < 16; r++) Lacc[r] = 0.f;
  float mrow = -INFINITY;

  const int sr8 = tid >> 3, sp8 = tid & 7;
  const int sr16 = tid >> 4, sp16 = tid & 15;

  f16x8 ones;  // all-ones A fragment for the denominator MFMA
#pragma unroll
  for (int ii = 0; ii < 8; ii++) ones[ii] = (f16)1.0f;

  for (int j0 = 0; j0 < kT; j0 += 128) {
    __syncthreads();
    // stage K tile [j][d]
#pragma unroll
    for (int u = 0; u < 4; u++) {
      const int jr = sr8 + u * 32;
      *(f16x8*)&Ks[jr][sp8 * 8] = *(const f16x8*)(Kh + (bt0 + j0 + jr) * kD + h * 64 + sp8 * 8);
    }
    // stage V^T tile [d][j]
#pragma unroll
    for (int u = 0; u < 4; u++) {
      const int d = sr16 + u * 16;
      *(f16x8*)&Vs[d][sp16 * 8] =
          *(const f16x8*)(Vt + (size_t)(h * 64 + d) * kM + bt0 + j0 + sp16 * 8);
    }
    __syncthreads();

#pragma unroll
    for (int c = 0; c < 2; c++) {  // 64-j chunks
      // S^T = K Q^T : two 32-j tiles, contraction over d in 4 chunks of 16
      f32x16 s[2];
#pragma unroll
      for (int jt = 0; jt < 2; jt++)
#pragma unroll
        for (int r = 0; r < 16; r++) s[jt][r] = 0.f;
#pragma unroll
      for (int kc = 0; kc < 4; kc++) {
        f16x8 ka = *(const f16x8*)&Ks[c * 64 + l31][kc * 16 + hi8];
        f16x8 kb = *(const f16x8*)&Ks[c * 64 + 32 + l31][kc * 16 + hi8];
        s[0] = MFMA32F16(ka, qf[kc], s[0]);
        s[1] = MFMA32F16(kb, qf[kc], s[1]);
      }

      // online softmax with defer-max: lane owns column q; rows split lane<->lane^32
      float mx = s[0][0];
#pragma unroll
      for (int jt = 0; jt < 2; jt++)
#pragma unroll
        for (int r = 0; r < 16; r++) mx = fmaxf(mx, s[jt][r]);
      mx = fmaxf(mx, __shfl_xor(mx, 32));
      if (!__all(mx <= mrow + 8.0f)) {  // raise running max only when needed
        const float mnew = fmaxf(mrow, mx);
        const float al = __builtin_amdgcn_exp2f(mrow - mnew);
        mrow = mnew;
#pragma unroll
        for (int dt = 0; dt < 2; dt++)
#pragma unroll
          for (int r = 0; r < 16; r++) Oat[dt][r] *= al;
        Lacc[0] *= al;
      }

#pragma unroll
      for (int jt = 0; jt < 2; jt++) {
        // exp2 + pack: w[k] covers j-row pairs (2k,2k+1) of this jt tile's lane half
        unsigned w[8];
#pragma unroll
        for (int k = 0; k < 8; k++) {
          const float e0 = __builtin_amdgcn_exp2f(s[jt][2 * k] - mrow);
          const float e1 = __builtin_amdgcn_exp2f(s[jt][2 * k + 1] - mrow);
          w[k] = pk_f16(e0, e1);
        }
        // P^T B-fragments via permlane32_swap:
        //  even 16-j half: words = {sw(w0,w2).x, sw(w1,w3).x, sw(w0,w2).y, sw(w1,w3).y}
        //  odd  16-j half: same with w4..w7
        i32x2 a0 = pl32swap(w[0], w[2]);
        i32x2 a1 = pl32swap(w[1], w[3]);
        i32x2 b0 = pl32swap(w[4], w[6]);
        i32x2 b1 = pl32swap(w[5], w[7]);
        u32x4 ue = {(unsigned)a0.x, (unsigned)a1.x, (unsigned)a0.y, (unsigned)a1.y};
        u32x4 uo = {(unsigned)b0.x, (unsigned)b1.x, (unsigned)b0.y, (unsigned)b1.y};
        const f16x8 fe = __builtin_bit_cast(f16x8, ue);
        const f16x8 fo = __builtin_bit_cast(f16x8, uo);
        // O^T += V^T @ P^T over this jt tile's two 16-j chunks; denominator via ones@P^T
#pragma unroll
        for (int dt = 0; dt < 2; dt++) {
          f16x8 ve = *(const f16x8*)&Vs[dt * 32 + l31][c * 64 + jt * 32 + hi8];
          Oat[dt] = MFMA32F16(ve, fe, Oat[dt]);
        }
        Lacc = MFMA32F16(ones, fe, Lacc);
#pragma unroll
        for (int dt = 0; dt < 2; dt++) {
          f16x8 vo = *(const f16x8*)&Vs[dt * 32 + l31][c * 64 + jt * 32 + 16 + hi8];
          Oat[dt] = MFMA32F16(vo, fo, Oat[dt]);
        }
        Lacc = MFMA32F16(ones, fo, Lacc);
      }
    }
  }

  // scale attention by (1-w)/l (lane-uniform!) and add const-positional region from the
  // precomputed V^T prefix sums: tiles j0 <= qblk-256 == first (qt-1) tiles, identical
  // for all waves. Vpre[p] = colsum over first p tiles; p = max(qt-1, 0) (Vpre[0] = 0).
  {
    const float inv = one_m_w / Lacc[0];
    const int pidx = (qt >= 1) ? (qt - 1) : 0;
    const float* vp = Vpre + ((size_t)(bi * 16 + h) * 16 + pidx) * 64;
#pragma unroll
    for (int dt = 0; dt < 2; dt++)
#pragma unroll
      for (int r = 0; r < 16; r++) {
        const int dd = dt * 32 + (r & 3) + 8 * (r >> 2) + 4 * hi;
        Oat[dt][r] = Oat[dt][r] * inv + tab100f * vp[dd];
      }
  }

  // near-diagonal positional band: restage the two boundary V tiles, table B-fragments
#pragma unroll
  for (int tb = 0; tb < 2; tb++) {
    const int jb = qblk - 128 + tb * 128;  // block-uniform
    if (jb >= 0) {
      __syncthreads();
#pragma unroll
      for (int u = 0; u < 4; u++) {
        const int d = sr16 + u * 16;
        *(f16x8*)&Vs[d][sp16 * 8] =
            *(const f16x8*)(Vt + (size_t)(h * 64 + d) * kM + bt0 + jb + sp16 * 8);
      }
      __syncthreads();
#pragma unroll
      for (int jc = 0; jc < 8; jc++) {
        f16x8 wf;
#pragma unroll
        for (int e = 0; e < 8; e++) {
          const int j = jb + jc * 16 + hi8 + e;
          const int dlt = qg - j;
          float pv = 0.0f;
          if (dlt > 0) pv = tab_s[dlt > kMAXL ? kMAXL : dlt];
          wf[e] = (f16)pv;
        }
#pragma unroll
        for (int dt = 0; dt < 2; dt++) {
          f16x8 vf = *(const f16x8*)&Vs[dt * 32 + l31][jc * 16 + hi8];
          Oat[dt] = MFMA32F16(vf, wf, Oat[dt]);
        }
      }
    }
  }

  // epilogue: un-transpose O^T -> Pb[q][d] via per-wave LDS scratch (reuses Ks; all
  // waves passed the band barriers, so Ks is dead). Wave w owns Ks rows [32w,32w+32).
  {
    f16* sw = &Ks[wave * 32][0];  // viewed as [32 q][68]
#pragma unroll
    for (int dt = 0; dt < 2; dt++)
#pragma unroll
      for (int r = 0; r < 16; r++) {
        const int d = dt * 32 + (r & 3) + 8 * (r >> 2) + 4 * hi;
        sw[l31 * 68 + d] = (f16)Oat[dt][r];
      }
    // in-wave LDS write->read ordering handled by compiler (lgkmcnt)
#pragma unroll
    for (int u = 0; u < 4; u++) {
      const int qr = lane >> 1;
      const int c0 = (lane & 1) * 32 + u * 8;
      f16x8 ofr = *(const f16x8*)&sw[qr * 68 + c0];
      *(f16x8*)(Pb + (bt0 + qw0 + qr) * kD + h * 64 + c0) = ofr;
    }
  }
}

extern "C" void kernel_launch(void* const* d_in, const int* in_sizes, int n_in, void* d_out,
                              int out_size, void* d_ws, size_t ws_size, hipStream_t stream) {
  const float* x = (const float*)d_in[0];
  const float* mu = (const float*)d_in[1];
  const float* lam = (const float*)d_in[2];
  const float* g1 = (const float*)d_in[3];
  const float* g2 = (const float*)d_in[4];
  const float* th1 = (const float*)d_in[5];
  const float* th2 = (const float*)d_in[6];
  const float* Wq = (const float*)d_in[7];
  const float* bq = (const float*)d_in[8];
  const float* Wk = (const float*)d_in[9];
  const float* bk = (const float*)d_in[10];
  const float* Wv = (const float*)d_in[11];
  const float* bv = (const float*)d_in[12];
  const float* Wf = (const float*)d_in[13];
  const float* bf = (const float*)d_in[14];

  if (ws_size < WS_NEED) return;  // cannot run without scratch

  char* ws = (char*)d_ws;
  float* tab = (float*)(ws + OFF_TAB);
  f16* xh = (f16*)(ws + OFF_XH);
  f16* wqh = (f16*)(ws + OFF_WQ);
  f16* wkh = (f16*)(ws + OFF_WK);
  f16* wvh = (f16*)(ws + OFF_WV);
  f16* wfh = (f16*)(ws + OFF_WF);
  f16* Qp = (f16*)(ws + OFF_Q);
  f16* Kp = (f16*)(ws + OFF_K);
  f16* Vtp = (f16*)(ws + OFF_V);
  f16* Pbp = (f16*)(ws + OFF_P);
  float* Vpre = (float*)(ws + OFF_VPRE);  // aliases xh (dead after qkv)

  // fused preprocessing: tab + all fp32->fp16 converts in ONE dispatch
  pre_kernel<<<3072, 256, 0, stream>>>(x, Wq, Wk, Wv, Wf, mu, lam, g1, g2, th1, th2, xh, wqh,
                                       wkh, wvh, wfh, tab);

  // fused Q/K/V^T projections (Q scaled by log2(e) after bias for exp2 softmax).
  qkv_kernel<<<1536, 256, 0, stream>>>(xh, wqh, wkh, wvh, bq, bk, bv, Qp, Kp, Vtp);

  // V^T prefix column sums for the const-positional region (writes over dead xh).
  vsum_kernel<<<256, 1024, 0, stream>>>(Vtp, Vpre);

  attn_kernel<<<1024, 256, 0, stream>>>(Qp, Kp, Vtp, tab, Vpre, Pbp);

  gemm_bt_kernel<float, false><<<512, 256, 0, stream>>>(Pbp, wfh, bf, (float*)d_out, kM, kD, kD,
                                                        1.0f);
}